// Round 1
// baseline (21330.553 us; speedup 1.0000x reference)
//
#include <hip/hip_runtime.h>
#include <math.h>

// Problem constants
#define BB 8
#define MM 2048
#define KM 1024
#define DD 256
#define HH 4
#define HD 64
#define NLAYER 2
#define BN (BB*KM)        // 8192 rows per "decoder half"
#define N2 (2*BN)         // 16384 rows d0||d1
#define CG_ITERS 20

__device__ __forceinline__ float softplusf(float x) {
  return fmaxf(x, 0.f) + log1pf(expf(-fabsf(x)));
}

// ---------------- gather: f_i, xy0, xy1 ----------------
__global__ __launch_bounds__(256) void gather_kernel(
    const float* __restrict__ fa, const float* __restrict__ fb,
    const int* __restrict__ matches, const float* __restrict__ ka,
    const float* __restrict__ kb, float* __restrict__ F,
    float* __restrict__ xy0, float* __restrict__ xy1)
{
  int si = blockIdx.x;             // s*1024 + i
  int s  = si >> 10;
  int t  = threadIdx.x;
  int ia = matches[(size_t)si*2+0];
  int ib = matches[(size_t)si*2+1];
  F[(size_t)si*DD + t] = fb[((size_t)s*MM + ib)*DD + t]
                       - fa[((size_t)s*MM + ia)*DD + t];
  if (t == 0) {
    xy0[(size_t)si*2+0] = ka[((size_t)s*MM + ia)*2+0];
    xy0[(size_t)si*2+1] = ka[((size_t)s*MM + ia)*2+1];
    xy1[(size_t)si*2+0] = kb[((size_t)s*MM + ib)*2+0];
    xy1[(size_t)si*2+1] = kb[((size_t)s*MM + ib)*2+1];
  }
}

// ---------------- positional encoding ----------------
// enc layout: (s, cs{cos,sin}, i, d) ; enc[((s*2+cs)*KM+i)*HD + d], d pairs share p=d/2
__global__ __launch_bounds__(64) void posenc_kernel(
    const float* __restrict__ xy, const float* __restrict__ Wr,
    float* __restrict__ enc)
{
  int si = blockIdx.x; int s = si >> 10, i = si & 1023;
  int d = threadIdx.x; int p = d >> 1;
  float x = xy[(size_t)si*2], y = xy[(size_t)si*2+1];
  float pr = Wr[p*2]*x + Wr[p*2+1]*y;
  enc[(((size_t)s*2+0)*KM + i)*HD + d] = cosf(pr);
  enc[(((size_t)s*2+1)*KM + i)*HD + d] = sinf(pr);
}

// ---------------- Kmat + rowsum ----------------
__global__ __launch_bounds__(256) void kmat_kernel(
    const float* __restrict__ xy0, const float* __restrict__ beta_ptr,
    float* __restrict__ Km, float* __restrict__ rowsum)
{
  __shared__ float red[256];
  int si = blockIdx.x; int s = si >> 10;
  int t = threadIdx.x;
  float beta_r = softplusf(beta_ptr[0]);
  float xi = xy0[(size_t)si*2], yi = xy0[(size_t)si*2+1];
  const float* xys = xy0 + (size_t)s*KM*2;
  float sum = 0.f;
  for (int jj = 0; jj < 4; ++jj) {
    int j = jj*256 + t;
    float dx = xi - xys[j*2], dy = yi - xys[j*2+1];
    float v = expf(-beta_r*(dx*dx + dy*dy));
    Km[(size_t)si*KM + j] = v;
    sum += v;
  }
  red[t] = sum; __syncthreads();
  for (int s2 = 128; s2 > 0; s2 >>= 1) { if (t < s2) red[t] += red[t+s2]; __syncthreads(); }
  if (t == 0) rowsum[si] = red[0] + 1e-6f;
}

// ---------------- batched square GEMM: C = Kmat[z] @ B (+lam*B) (/rowsum) ----------------
__global__ __launch_bounds__(256) void gemm_bat_kernel(
    const float* __restrict__ Abat, const float* __restrict__ Bm,
    float* __restrict__ Cm, const float* __restrict__ lam_ptr,
    const float* __restrict__ rowsum)
{
  __shared__ float As[16][64];
  __shared__ float Bs[16][64];
  int t = threadIdx.x;
  int z = blockIdx.z;
  const float* A = Abat + (size_t)z * KM * KM;
  int row0 = blockIdx.x * 64;
  int col0 = blockIdx.y * 64;
  int ti = t & 15, tj = t >> 4;
  float acc[4][4] = {};
  for (int k0 = 0; k0 < KM; k0 += 16) {
#pragma unroll
    for (int p = 0; p < 4; ++p) {
      int l = p*256 + t;
      int kkA = l & 15, iA = l >> 4;
      As[kkA][iA] = A[(size_t)(row0+iA)*KM + (k0+kkA)];
      int jB = t & 63, kkB = p*4 + (t >> 6);
      Bs[kkB][jB] = Bm[((size_t)z*KM + k0+kkB)*DD + col0 + jB];
    }
    __syncthreads();
#pragma unroll
    for (int kk = 0; kk < 16; ++kk) {
      float a[4], b[4];
#pragma unroll
      for (int u = 0; u < 4; ++u) a[u] = As[kk][ti*4+u];
#pragma unroll
      for (int u = 0; u < 4; ++u) b[u] = Bs[kk][tj*4+u];
#pragma unroll
      for (int x = 0; x < 4; ++x)
#pragma unroll
        for (int y = 0; y < 4; ++y) acc[x][y] += a[x]*b[y];
    }
    __syncthreads();
  }
  float lamv = 0.f;
  if (lam_ptr) lamv = softplusf(lam_ptr[0]) + 1e-6f;
#pragma unroll
  for (int x = 0; x < 4; ++x) {
    int r = row0 + ti*4 + x;
#pragma unroll
    for (int y = 0; y < 4; ++y) {
      int c = col0 + tj*4 + y;
      size_t oidx = ((size_t)z*KM + r)*DD + c;
      float v = acc[x][y];
      if (lam_ptr) v += lamv * Bm[oidx];
      if (rowsum) v /= rowsum[(size_t)z*KM + r];
      Cm[oidx] = v;
    }
  }
}

// ---------------- generic weight GEMM: C = [A|A2] @ W.T + bias, epilogues ----------------
// epi: 0 none, 1 scale, 2 relu ; resid != null -> += resid
__global__ __launch_bounds__(256) void gemm_w_kernel(
    const float* __restrict__ A, const float* __restrict__ A2, int K1, int K,
    const float* __restrict__ W, const float* __restrict__ bias,
    float* __restrict__ C, int O,
    const float* __restrict__ resid, float scale, int epi)
{
  __shared__ float As[16][64];
  __shared__ float Ws[16][64];
  int t = threadIdx.x;
  int row0 = blockIdx.x * 64;
  int col0 = blockIdx.y * 64;
  int ti = t & 15, tj = t >> 4;
  float acc[4][4] = {};
  int K2 = K - K1;
  for (int k0 = 0; k0 < K; k0 += 16) {
#pragma unroll
    for (int p = 0; p < 4; ++p) {
      int l = p*256 + t;
      int kk = l & 15, i = l >> 4;
      int kg = k0 + kk;
      int r = row0 + i;
      float v;
      if (kg < K1) v = A[(size_t)r*K1 + kg];
      else         v = A2[(size_t)r*K2 + (kg - K1)];
      As[kk][i] = v;
      Ws[kk][i] = W[(size_t)(col0+i)*K + kg];
    }
    __syncthreads();
#pragma unroll
    for (int kk = 0; kk < 16; ++kk) {
      float a[4], b[4];
#pragma unroll
      for (int u = 0; u < 4; ++u) a[u] = As[kk][ti*4+u];
#pragma unroll
      for (int u = 0; u < 4; ++u) b[u] = Ws[kk][tj*4+u];
#pragma unroll
      for (int x = 0; x < 4; ++x)
#pragma unroll
        for (int y = 0; y < 4; ++y) acc[x][y] += a[x]*b[y];
    }
    __syncthreads();
  }
#pragma unroll
  for (int x = 0; x < 4; ++x) {
    int r = row0 + ti*4 + x;
#pragma unroll
    for (int y = 0; y < 4; ++y) {
      int c = col0 + tj*4 + y;
      float v = acc[x][y] + bias[c];
      if (epi == 1) v *= scale;
      else if (epi == 2) v = fmaxf(v, 0.f);
      if (resid) v += resid[(size_t)r*O + c];
      C[(size_t)r*O + c] = v;
    }
  }
}

// ---------------- CG helpers ----------------
__global__ __launch_bounds__(256) void cg_init_kernel(
    const float* __restrict__ F, float* __restrict__ X,
    float* __restrict__ R, float* __restrict__ P)
{
  size_t idx = (size_t)blockIdx.x*256 + threadIdx.x;
  float f = F[idx];
  X[idx] = 0.f; R[idx] = f; P[idx] = f;
}

__global__ __launch_bounds__(256) void zero_kernel(float* __restrict__ p, int n) {
  int idx = blockIdx.x*256 + threadIdx.x;
  if (idx < n) p[idx] = 0.f;
}

__global__ __launch_bounds__(256) void copy_kernel(
    float* __restrict__ dst, const float* __restrict__ src, int n)
{
  size_t idx = (size_t)blockIdx.x*256 + threadIdx.x;
  if (idx < (size_t)n) dst[idx] = src[idx];
}

// per-(sample,col) dot:  out[s*256+j] += sum_i A[s,i,j]*Bv[s,i,j]
__global__ __launch_bounds__(256) void cg_dot_kernel(
    const float* __restrict__ A, const float* __restrict__ Bv,
    float* __restrict__ out)
{
  int blk = blockIdx.x;          // s*256 + chunk
  int s = blk >> 8;
  int chunk = blk & 255;
  int j = threadIdx.x;
  size_t rbase = ((size_t)s*KM + chunk*4)*DD;
  float acc = 0.f;
#pragma unroll
  for (int u = 0; u < 4; ++u)
    acc += A[rbase + (size_t)u*DD + j] * Bv[rbase + (size_t)u*DD + j];
  atomicAdd(&out[s*DD + j], acc);
}

__global__ __launch_bounds__(256) void cg_update_xr_kernel(
    float* __restrict__ X, float* __restrict__ R,
    const float* __restrict__ P, const float* __restrict__ AP,
    const float* __restrict__ rr, const float* __restrict__ pap)
{
  size_t idx = (size_t)blockIdx.x*256 + threadIdx.x;
  int j = threadIdx.x;
  int s = blockIdx.x >> 10;
  float den = pap[s*DD + j];
  float num = rr[s*DD + j];
  float alpha = (den > 0.f) ? num/den : 0.f;
  X[idx] += alpha * P[idx];
  R[idx] -= alpha * AP[idx];
}

__global__ __launch_bounds__(256) void cg_update_p_kernel(
    float* __restrict__ P, const float* __restrict__ R,
    const float* __restrict__ rrold, const float* __restrict__ rrnew)
{
  size_t idx = (size_t)blockIdx.x*256 + threadIdx.x;
  int j = threadIdx.x;
  int s = blockIdx.x >> 10;
  float o = rrold[s*DD + j], nn = rrnew[s*DD + j];
  float beta = (o > 0.f) ? nn/o : 0.f;
  P[idx] = R[idx] + beta * P[idx];
}

// ---------------- RoPE + qkv split ----------------
// qkv row layout: channel (h*64+d)*3 + {0,1,2}; outputs row-major col = h*64+d
__global__ __launch_bounds__(256) void rope_split_kernel(
    const float* __restrict__ qkv, const float* __restrict__ enc0,
    const float* __restrict__ enc1, float* __restrict__ Qo,
    float* __restrict__ Ko, float* __restrict__ Vo)
{
  int r = blockIdx.x;            // stream*KM + i ; stream in [0,16)
  int c = threadIdx.x;           // h*64+d
  int ts = r >> 10, i = r & 1023;
  int h = c >> 6, d = c & 63;
  const float* enc = (ts < BB) ? enc0 : enc1;
  int s = (ts < BB) ? ts : ts - BB;
  float cs = enc[(((size_t)s*2+0)*KM + i)*HD + d];
  float sn = enc[(((size_t)s*2+1)*KM + i)*HD + d];
  size_t base = (size_t)r*768 + (size_t)h*192;
  float q  = qkv[base + d*3 + 0];
  float k  = qkv[base + d*3 + 1];
  float v  = qkv[base + d*3 + 2];
  int dp = d ^ 1;
  float qp = qkv[base + dp*3 + 0];
  float kp = qkv[base + dp*3 + 1];
  float rq = (d & 1) ? qp : -qp;
  float rk = (d & 1) ? kp : -kp;
  size_t o = (size_t)r*DD + c;
  Qo[o] = q*cs + rq*sn;
  Ko[o] = k*cs + rk*sn;
  Vo[o] = v;
}

// ---------------- attention: out[i] = softmax_j(q_i.k_j * scale) @ V ----------------
// all operands row-major (stream*KM + n)*256, col h*64+d
__global__ __launch_bounds__(256) void attn_kernel(
    const float* __restrict__ Q, const float* __restrict__ Kt,
    const float* __restrict__ V, float* __restrict__ Out, float scale)
{
  __shared__ float qs[HD];
  __shared__ float ss[KM];
  __shared__ float red[256];
  __shared__ float po[4][HD];
  int i = blockIdx.x, h = blockIdx.y, z = blockIdx.z;
  int t = threadIdx.x;
  size_t base = (size_t)z*KM*DD + h*HD;
  if (t < HD) qs[t] = Q[base + (size_t)i*DD + t];
  __syncthreads();
  for (int jj = 0; jj < 4; ++jj) {
    int j = jj*256 + t;
    const float* kr = Kt + base + (size_t)j*DD;
    float s = 0.f;
#pragma unroll
    for (int d = 0; d < HD; ++d) s += qs[d]*kr[d];
    ss[j] = s * scale;
  }
  __syncthreads();
  float m = -1e30f;
  for (int jj = 0; jj < 4; ++jj) m = fmaxf(m, ss[jj*256+t]);
  red[t] = m; __syncthreads();
  for (int s2 = 128; s2 > 0; s2 >>= 1) { if (t < s2) red[t] = fmaxf(red[t], red[t+s2]); __syncthreads(); }
  m = red[0]; __syncthreads();
  float sum = 0.f;
  for (int jj = 0; jj < 4; ++jj) {
    float p = expf(ss[jj*256+t] - m);
    ss[jj*256+t] = p;
    sum += p;
  }
  red[t] = sum; __syncthreads();
  for (int s2 = 128; s2 > 0; s2 >>= 1) { if (t < s2) red[t] += red[t+s2]; __syncthreads(); }
  float denom = red[0];
  int d = t & 63, g = t >> 6;
  float accv = 0.f;
  for (int j = g*256; j < (g+1)*256; ++j)
    accv += ss[j] * V[base + (size_t)j*DD + d];
  po[g][d] = accv;
  __syncthreads();
  if (t < HD) {
    float v = (po[0][t] + po[1][t] + po[2][t] + po[3][t]) / denom;
    Out[((size_t)z*KM + i)*DD + h*HD + t] = v;
  }
}

// ---------------- in-place LayerNorm + exact GELU over width 512 ----------------
__global__ __launch_bounds__(256) void ln_gelu_kernel(
    float* __restrict__ Hb, const float* __restrict__ g,
    const float* __restrict__ be)
{
  __shared__ float red[256];
  int r = blockIdx.x, t = threadIdx.x;
  float x0 = Hb[(size_t)r*512 + t];
  float x1 = Hb[(size_t)r*512 + 256 + t];
  red[t] = x0 + x1; __syncthreads();
  for (int s2 = 128; s2 > 0; s2 >>= 1) { if (t < s2) red[t] += red[t+s2]; __syncthreads(); }
  float mu = red[0] * (1.f/512.f); __syncthreads();
  float d0 = x0 - mu, d1 = x1 - mu;
  red[t] = d0*d0 + d1*d1; __syncthreads();
  for (int s2 = 128; s2 > 0; s2 >>= 1) { if (t < s2) red[t] += red[t+s2]; __syncthreads(); }
  float rstd = rsqrtf(red[0]*(1.f/512.f) + 1e-5f);
  float h0 = d0*rstd*g[t] + be[t];
  float h1 = d1*rstd*g[256+t] + be[256+t];
  h0 = 0.5f*h0*(1.f + erff(h0*0.70710678118f));
  h1 = 0.5f*h1*(1.f + erff(h1*0.70710678118f));
  Hb[(size_t)r*512 + t] = h0;
  Hb[(size_t)r*512 + 256 + t] = h1;
}

// ---------------- final head 2: sigmoid(h @ pW2.T + pb2) ----------------
__global__ __launch_bounds__(256) void head2_kernel(
    const float* __restrict__ Hb, const float* __restrict__ w,
    const float* __restrict__ b, float* __restrict__ out)
{
  int r = blockIdx.x*256 + threadIdx.x;   // 8192 rows
  float acc = b[0];
#pragma unroll
  for (int k = 0; k < 64; ++k) acc += Hb[(size_t)r*64 + k]*w[k];
  out[r] = 1.f/(1.f + expf(-acc));
}

// ---------------- host ----------------
static void launch_gemm(const float* A, const float* A2, int K1, int K,
                        const float* W, const float* bias, float* C, int O,
                        int Nrows, const float* resid, float scale, int epi,
                        hipStream_t stream)
{
  dim3 grid(Nrows/64, O/64);
  gemm_w_kernel<<<grid, 256, 0, stream>>>(A, A2, K1, K, W, bias, C, O, resid, scale, epi);
}

extern "C" void kernel_launch(void* const* d_in, const int* in_sizes, int n_in,
                              void* d_out, int out_size, void* d_ws, size_t ws_size,
                              hipStream_t stream)
{
  (void)in_sizes; (void)n_in; (void)out_size; (void)ws_size;
  const float* fa      = (const float*)d_in[0];
  const float* fb      = (const float*)d_in[1];
  const int*   matches = (const int*)d_in[2];
  const float* ka      = (const float*)d_in[3];
  const float* kb      = (const float*)d_in[4];
  const float* lam     = (const float*)d_in[5];
  const float* beta    = (const float*)d_in[6];
  const float* Wr      = (const float*)d_in[7];
  const float* pW1     = (const float*)d_in[8];
  const float* pb1     = (const float*)d_in[9];
  const float* pW2     = (const float*)d_in[10];
  const float* pb2     = (const float*)d_in[11];
  const float* sWqkv   = (const float*)d_in[12];
  const float* sbqkv   = (const float*)d_in[13];
  const float* sWo     = (const float*)d_in[14];
  const float* sbo     = (const float*)d_in[15];
  const float* sW1     = (const float*)d_in[16];
  const float* sb1     = (const float*)d_in[17];
  const float* sg      = (const float*)d_in[18];
  const float* sbe     = (const float*)d_in[19];
  const float* sW2     = (const float*)d_in[20];
  const float* sb2     = (const float*)d_in[21];
  const float* cWqk    = (const float*)d_in[22];
  const float* cbqk    = (const float*)d_in[23];
  const float* cWv     = (const float*)d_in[24];
  const float* cbv     = (const float*)d_in[25];
  const float* cWo     = (const float*)d_in[26];
  const float* cbo     = (const float*)d_in[27];
  const float* cW1     = (const float*)d_in[28];
  const float* cb1     = (const float*)d_in[29];
  const float* cgw     = (const float*)d_in[30];
  const float* cbe     = (const float*)d_in[31];
  const float* cW2     = (const float*)d_in[32];
  const float* cb2     = (const float*)d_in[33];

  float* ws = (float*)d_ws;
  // persistent region (floats)
  float* DCAT  = ws;                       // 2*BN*256 = 4,194,304
  float* ENC0  = ws + 4194304;             // 1,048,576
  float* ENC1  = ws + 5242880;             // 1,048,576
  float* XY0   = ws + 6291456;             // 16,384
  float* XY1   = ws + 6307840;             // 16,384
  float* ROWS  = ws + 6324224;             // 8,192
  float* RRA   = ws + 6332416;             // 2,048
  float* RRB   = ws + 6334464;             // 2,048
  float* PAP   = ws + 6336512;             // 2,048
  float* POOL  = ws + 6338560;             // 25,165,824  (total ~126 MB)

  // CG-phase aliases
  float* KMAT = POOL;                  // 8,388,608
  float* FBUF = POOL + 8388608;        // 2,097,152
  float* XB   = POOL + 10485760;
  float* RB   = POOL + 12582912;
  float* PB   = POOL + 14680064;
  float* APB  = POOL + 16777216;
  // transformer-phase aliases (CG buffers dead)
  float* QKV  = POOL;                  // 12,582,912 (16384x768)
  float* QR   = POOL + 12582912;       // 4,194,304
  float* KR   = POOL + 16777216;       // 4,194,304
  float* VB   = POOL + 20971520;       // 4,194,304
  float* ATTO = POOL;                  // 4,194,304 (QKV dead post-rope... post-attn)
  float* MSG  = POOL + 4194304;        // 4,194,304
  float* H1   = POOL + 8388608;        // 8,388,608 (16384x512)
  // cross-phase aliases
  float* QKB   = POOL;                 // 4,194,304
  float* VB2   = POOL + 4194304;       // 4,194,304
  float* ATTO2 = POOL + 8388608;       // 4,194,304
  float* MSG2  = POOL + 12582912;      // 4,194,304
  float* H1C   = POOL + 16777216;      // 8,388,608
  float* HBUF  = POOL;                 // 524,288 (8192x64)

  const float sc = 0.35355339059327373f;   // 64^-0.25

  // ---- gather / posenc / Kmat ----
  gather_kernel<<<BN, 256, 0, stream>>>(fa, fb, matches, ka, kb, FBUF, XY0, XY1);
  posenc_kernel<<<BN, 64, 0, stream>>>(XY0, Wr, ENC0);
  posenc_kernel<<<BN, 64, 0, stream>>>(XY1, Wr, ENC1);
  kmat_kernel<<<BN, 256, 0, stream>>>(XY0, beta, KMAT, ROWS);

  // ---- CG solve (Kmat + lam I) X = F, 256 RHS per sample ----
  cg_init_kernel<<<BN, 256, 0, stream>>>(FBUF, XB, RB, PB);
  zero_kernel<<<8, 256, 0, stream>>>(RRA, BB*DD);
  cg_dot_kernel<<<BB*256, 256, 0, stream>>>(RB, RB, RRA);
  for (int it = 0; it < CG_ITERS; ++it) {
    gemm_bat_kernel<<<dim3(16,4,BB), 256, 0, stream>>>(KMAT, PB, APB, lam, nullptr);
    zero_kernel<<<8, 256, 0, stream>>>(PAP, BB*DD);
    cg_dot_kernel<<<BB*256, 256, 0, stream>>>(PB, APB, PAP);
    cg_update_xr_kernel<<<BN, 256, 0, stream>>>(XB, RB, PB, APB, RRA, PAP);
    zero_kernel<<<8, 256, 0, stream>>>(RRB, BB*DD);
    cg_dot_kernel<<<BB*256, 256, 0, stream>>>(RB, RB, RRB);
    cg_update_p_kernel<<<BN, 256, 0, stream>>>(PB, RB, RRA, RRB);
    copy_kernel<<<8, 256, 0, stream>>>(RRA, RRB, BB*DD);
  }

  // ---- d0 = f_i ; d1 = rownorm(Kmat) @ C ----
  copy_kernel<<<BN, 256, 0, stream>>>(DCAT, FBUF, BN*DD);
  gemm_bat_kernel<<<dim3(16,4,BB), 256, 0, stream>>>(KMAT, XB, DCAT + (size_t)BN*DD, nullptr, ROWS);

  // ---- transformer layers ----
  for (int l = 0; l < NLAYER; ++l) {
    // self block (d0 and d1 batched: 16384 rows, shared weights)
    launch_gemm(DCAT, nullptr, DD, DD, sWqkv + (size_t)l*768*DD, sbqkv + l*768,
                QKV, 768, N2, nullptr, 1.f, 0, stream);
    rope_split_kernel<<<N2, 256, 0, stream>>>(QKV, ENC0, ENC1, QR, KR, VB);
    attn_kernel<<<dim3(KM, HH, 16), 256, 0, stream>>>(QR, KR, VB, ATTO, 0.125f);
    launch_gemm(ATTO, nullptr, DD, DD, sWo + (size_t)l*DD*DD, sbo + l*DD,
                MSG, DD, N2, nullptr, 1.f, 0, stream);
    launch_gemm(DCAT, MSG, DD, 512, sW1 + (size_t)l*512*512, sb1 + l*512,
                H1, 512, N2, nullptr, 1.f, 0, stream);
    ln_gelu_kernel<<<N2, 256, 0, stream>>>(H1, sg + l*512, sbe + l*512);
    launch_gemm(H1, nullptr, 512, 512, sW2 + (size_t)l*DD*512, sb2 + l*DD,
                DCAT, DD, N2, DCAT, 1.f, 0, stream);
    // cross block
    launch_gemm(DCAT, nullptr, DD, DD, cWqk + (size_t)l*DD*DD, cbqk + l*DD,
                QKB, DD, N2, nullptr, sc, 1, stream);
    launch_gemm(DCAT, nullptr, DD, DD, cWv + (size_t)l*DD*DD, cbv + l*DD,
                VB2, DD, N2, nullptr, 1.f, 0, stream);
    attn_kernel<<<dim3(KM, HH, BB), 256, 0, stream>>>(QKB, QKB + (size_t)BN*DD,
                VB2 + (size_t)BN*DD, ATTO2, 1.f);
    attn_kernel<<<dim3(KM, HH, BB), 256, 0, stream>>>(QKB + (size_t)BN*DD, QKB,
                VB2, ATTO2 + (size_t)BN*DD, 1.f);
    launch_gemm(ATTO2, nullptr, DD, DD, cWo + (size_t)l*DD*DD, cbo + l*DD,
                MSG2, DD, N2, nullptr, 1.f, 0, stream);
    launch_gemm(DCAT, MSG2, DD, 512, cW1 + (size_t)l*512*512, cb1 + l*512,
                H1C, 512, N2, nullptr, 1.f, 0, stream);
    ln_gelu_kernel<<<N2, 256, 0, stream>>>(H1C, cgw + l*512, cbe + l*512);
    launch_gemm(H1C, nullptr, 512, 512, cW2 + (size_t)l*DD*512, cb2 + l*DD,
                DCAT, DD, N2, DCAT, 1.f, 0, stream);
  }

  // ---- head (d0 only = first BN rows of DCAT) ----
  launch_gemm(DCAT, nullptr, DD, DD, pW1, pb1, HBUF, 64, BN, nullptr, 1.f, 2, stream);
  head2_kernel<<<BN/256, 256, 0, stream>>>(HBUF, pW2, pb2, (float*)d_out);
}

// Round 2
// 5296.885 us; speedup vs baseline: 4.0270x; 4.0270x over previous
//
#include <hip/hip_runtime.h>
#include <math.h>

// Problem constants
#define BB 8
#define MM 2048
#define KM 1024
#define DD 256
#define HH 4
#define HD 64
#define NLAYER 2
#define BN (BB*KM)        // 8192 rows per "decoder half"
#define N2 (2*BN)         // 16384 rows d0||d1
#define CG_ITERS 16

__device__ __forceinline__ float softplusf(float x) {
  return fmaxf(x, 0.f) + log1pf(expf(-fabsf(x)));
}

// ---------------- gather: f_i, xy0, xy1 ----------------
__global__ __launch_bounds__(256) void gather_kernel(
    const float* __restrict__ fa, const float* __restrict__ fb,
    const int* __restrict__ matches, const float* __restrict__ ka,
    const float* __restrict__ kb, float* __restrict__ F,
    float* __restrict__ xy0, float* __restrict__ xy1)
{
  int si = blockIdx.x;             // s*1024 + i
  int s  = si >> 10;
  int t  = threadIdx.x;
  int ia = matches[(size_t)si*2+0];
  int ib = matches[(size_t)si*2+1];
  F[(size_t)si*DD + t] = fb[((size_t)s*MM + ib)*DD + t]
                       - fa[((size_t)s*MM + ia)*DD + t];
  if (t == 0) {
    xy0[(size_t)si*2+0] = ka[((size_t)s*MM + ia)*2+0];
    xy0[(size_t)si*2+1] = ka[((size_t)s*MM + ia)*2+1];
    xy1[(size_t)si*2+0] = kb[((size_t)s*MM + ib)*2+0];
    xy1[(size_t)si*2+1] = kb[((size_t)s*MM + ib)*2+1];
  }
}

// ---------------- positional encoding ----------------
__global__ __launch_bounds__(64) void posenc_kernel(
    const float* __restrict__ xy, const float* __restrict__ Wr,
    float* __restrict__ enc)
{
  int si = blockIdx.x; int s = si >> 10, i = si & 1023;
  int d = threadIdx.x; int p = d >> 1;
  float x = xy[(size_t)si*2], y = xy[(size_t)si*2+1];
  float pr = Wr[p*2]*x + Wr[p*2+1]*y;
  enc[(((size_t)s*2+0)*KM + i)*HD + d] = cosf(pr);
  enc[(((size_t)s*2+1)*KM + i)*HD + d] = sinf(pr);
}

// ---------------- Kmat + rowsum ----------------
__global__ __launch_bounds__(256) void kmat_kernel(
    const float* __restrict__ xy0, const float* __restrict__ beta_ptr,
    float* __restrict__ Km, float* __restrict__ rowsum)
{
  __shared__ float red[256];
  int si = blockIdx.x; int s = si >> 10;
  int t = threadIdx.x;
  float beta_r = softplusf(beta_ptr[0]);
  float xi = xy0[(size_t)si*2], yi = xy0[(size_t)si*2+1];
  const float* xys = xy0 + (size_t)s*KM*2;
  float sum = 0.f;
  for (int jj = 0; jj < 4; ++jj) {
    int j = jj*256 + t;
    float dx = xi - xys[j*2], dy = yi - xys[j*2+1];
    float v = expf(-beta_r*(dx*dx + dy*dy));
    Km[(size_t)si*KM + j] = v;
    sum += v;
  }
  red[t] = sum; __syncthreads();
  for (int s2 = 128; s2 > 0; s2 >>= 1) { if (t < s2) red[t] += red[t+s2]; __syncthreads(); }
  if (t == 0) rowsum[si] = red[0] + 1e-6f;
}

// ---------------- batched square GEMM: C = Kmat[z] @ B (+lam*B) (/rowsum) ----------------
// BK=32, padded LDS, float4 staging.
__global__ __launch_bounds__(256) void gemm_bat_kernel(
    const float* __restrict__ Abat, const float* __restrict__ Bm,
    float* __restrict__ Cm, const float* __restrict__ lam_ptr,
    const float* __restrict__ rowsum)
{
  __shared__ float As[32][68];
  __shared__ float Bs[32][68];
  int t = threadIdx.x;
  int z = blockIdx.z;
  const float* A = Abat + (size_t)z * KM * KM;
  int row0 = blockIdx.x * 64;
  int col0 = blockIdx.y * 64;
  int ti = t & 15, tj = t >> 4;
  float acc[4][4] = {};
  for (int k0 = 0; k0 < KM; k0 += 32) {
#pragma unroll
    for (int p = 0; p < 2; ++p) {
      int idx = p*256 + t;
      // A tile: 64 rows x 32 k, transpose-store
      int ar = idx >> 3, af = (idx & 7)*4;
      float4 av = *(const float4*)&A[(size_t)(row0+ar)*KM + k0 + af];
      As[af+0][ar] = av.x; As[af+1][ar] = av.y;
      As[af+2][ar] = av.z; As[af+3][ar] = av.w;
      // B tile: 32 k x 64 cols, direct store
      int bk = idx >> 4, bf = (idx & 15)*4;
      *(float4*)&Bs[bk][bf] =
        *(const float4*)&Bm[((size_t)z*KM + k0 + bk)*DD + col0 + bf];
    }
    __syncthreads();
#pragma unroll
    for (int kk = 0; kk < 32; ++kk) {
      float4 a4 = *(float4*)&As[kk][ti*4];
      float4 b4 = *(float4*)&Bs[kk][tj*4];
      float a[4] = {a4.x, a4.y, a4.z, a4.w};
      float b[4] = {b4.x, b4.y, b4.z, b4.w};
#pragma unroll
      for (int x = 0; x < 4; ++x)
#pragma unroll
        for (int y = 0; y < 4; ++y) acc[x][y] += a[x]*b[y];
    }
    __syncthreads();
  }
  float lamv = 0.f;
  if (lam_ptr) lamv = softplusf(lam_ptr[0]) + 1e-6f;
#pragma unroll
  for (int x = 0; x < 4; ++x) {
    int r = row0 + ti*4 + x;
#pragma unroll
    for (int y = 0; y < 4; ++y) {
      int c = col0 + tj*4 + y;
      size_t oidx = ((size_t)z*KM + r)*DD + c;
      float v = acc[x][y];
      if (lam_ptr) v += lamv * Bm[oidx];
      if (rowsum) v /= rowsum[(size_t)z*KM + r];
      Cm[oidx] = v;
    }
  }
}

// ---------------- generic weight GEMM: C = [A|A2] @ W.T + bias ----------------
// epi: 0 none, 1 scale, 2 relu ; resid != null -> += resid. BK=32 padded LDS.
__global__ __launch_bounds__(256) void gemm_w_kernel(
    const float* __restrict__ A, const float* __restrict__ A2, int K1, int K,
    const float* __restrict__ W, const float* __restrict__ bias,
    float* __restrict__ C, int O,
    const float* __restrict__ resid, float scale, int epi)
{
  __shared__ float As[32][68];
  __shared__ float Ws[32][68];
  int t = threadIdx.x;
  int row0 = blockIdx.x * 64;
  int col0 = blockIdx.y * 64;
  int ti = t & 15, tj = t >> 4;
  float acc[4][4] = {};
  int K2 = K - K1;
  for (int k0 = 0; k0 < K; k0 += 32) {
    const float* src; int stride; int kb;
    if (k0 < K1) { src = A;  stride = K1; kb = k0; }
    else         { src = A2; stride = K2; kb = k0 - K1; }
#pragma unroll
    for (int p = 0; p < 2; ++p) {
      int idx = p*256 + t;
      int ar = idx >> 3, af = (idx & 7)*4;
      float4 av = *(const float4*)&src[(size_t)(row0+ar)*stride + kb + af];
      As[af+0][ar] = av.x; As[af+1][ar] = av.y;
      As[af+2][ar] = av.z; As[af+3][ar] = av.w;
      float4 wv = *(const float4*)&W[(size_t)(col0+ar)*K + k0 + af];
      Ws[af+0][ar] = wv.x; Ws[af+1][ar] = wv.y;
      Ws[af+2][ar] = wv.z; Ws[af+3][ar] = wv.w;
    }
    __syncthreads();
#pragma unroll
    for (int kk = 0; kk < 32; ++kk) {
      float4 a4 = *(float4*)&As[kk][ti*4];
      float4 b4 = *(float4*)&Ws[kk][tj*4];
      float a[4] = {a4.x, a4.y, a4.z, a4.w};
      float b[4] = {b4.x, b4.y, b4.z, b4.w};
#pragma unroll
      for (int x = 0; x < 4; ++x)
#pragma unroll
        for (int y = 0; y < 4; ++y) acc[x][y] += a[x]*b[y];
    }
    __syncthreads();
  }
#pragma unroll
  for (int x = 0; x < 4; ++x) {
    int r = row0 + ti*4 + x;
#pragma unroll
    for (int y = 0; y < 4; ++y) {
      int c = col0 + tj*4 + y;
      float v = acc[x][y] + bias[c];
      if (epi == 1) v *= scale;
      else if (epi == 2) v = fmaxf(v, 0.f);
      if (resid) v += resid[(size_t)r*O + c];
      C[(size_t)r*O + c] = v;
    }
  }
}

// ---------------- CG helpers ----------------
__global__ __launch_bounds__(256) void cg_init_kernel(
    const float* __restrict__ F, float* __restrict__ X,
    float* __restrict__ R, float* __restrict__ P)
{
  size_t idx = (size_t)blockIdx.x*256 + threadIdx.x;
  float f = F[idx];
  X[idx] = 0.f; R[idx] = f; P[idx] = f;
}

__global__ __launch_bounds__(256) void zero_kernel(float* __restrict__ p, int n) {
  int idx = blockIdx.x*256 + threadIdx.x;
  if (idx < n) p[idx] = 0.f;
}

__global__ __launch_bounds__(256) void copy_kernel(
    float* __restrict__ dst, const float* __restrict__ src, int n)
{
  size_t idx = (size_t)blockIdx.x*256 + threadIdx.x;
  if (idx < (size_t)n) dst[idx] = src[idx];
}

__global__ __launch_bounds__(256) void cg_dot_kernel(
    const float* __restrict__ A, const float* __restrict__ Bv,
    float* __restrict__ out)
{
  int blk = blockIdx.x;          // s*256 + chunk
  int s = blk >> 8;
  int chunk = blk & 255;
  int j = threadIdx.x;
  size_t rbase = ((size_t)s*KM + chunk*4)*DD;
  float acc = 0.f;
#pragma unroll
  for (int u = 0; u < 4; ++u)
    acc += A[rbase + (size_t)u*DD + j] * Bv[rbase + (size_t)u*DD + j];
  atomicAdd(&out[s*DD + j], acc);
}

__global__ __launch_bounds__(256) void cg_update_xr_kernel(
    float* __restrict__ X, float* __restrict__ R,
    const float* __restrict__ P, const float* __restrict__ AP,
    const float* __restrict__ rr, const float* __restrict__ pap)
{
  size_t idx = (size_t)blockIdx.x*256 + threadIdx.x;
  int j = threadIdx.x;
  int s = blockIdx.x >> 10;
  float den = pap[s*DD + j];
  float num = rr[s*DD + j];
  float alpha = (den > 0.f) ? num/den : 0.f;
  X[idx] += alpha * P[idx];
  R[idx] -= alpha * AP[idx];
}

__global__ __launch_bounds__(256) void cg_update_p_kernel(
    float* __restrict__ P, const float* __restrict__ R,
    const float* __restrict__ rrold, const float* __restrict__ rrnew)
{
  size_t idx = (size_t)blockIdx.x*256 + threadIdx.x;
  int j = threadIdx.x;
  int s = blockIdx.x >> 10;
  float o = rrold[s*DD + j], nn = rrnew[s*DD + j];
  float beta = (o > 0.f) ? nn/o : 0.f;
  P[idx] = R[idx] + beta * P[idx];
}

// ---------------- RoPE + qkv split ----------------
__global__ __launch_bounds__(256) void rope_split_kernel(
    const float* __restrict__ qkv, const float* __restrict__ enc0,
    const float* __restrict__ enc1, float* __restrict__ Qo,
    float* __restrict__ Ko, float* __restrict__ Vo)
{
  int r = blockIdx.x;            // stream*KM + i ; stream in [0,16)
  int c = threadIdx.x;           // h*64+d
  int ts = r >> 10, i = r & 1023;
  int h = c >> 6, d = c & 63;
  const float* enc = (ts < BB) ? enc0 : enc1;
  int s = (ts < BB) ? ts : ts - BB;
  float cs = enc[(((size_t)s*2+0)*KM + i)*HD + d];
  float sn = enc[(((size_t)s*2+1)*KM + i)*HD + d];
  size_t base = (size_t)r*768 + (size_t)h*192;
  float q  = qkv[base + d*3 + 0];
  float k  = qkv[base + d*3 + 1];
  float v  = qkv[base + d*3 + 2];
  int dp = d ^ 1;
  float qp = qkv[base + dp*3 + 0];
  float kp = qkv[base + dp*3 + 1];
  float rq = (d & 1) ? qp : -qp;
  float rk = (d & 1) ? kp : -kp;
  size_t o = (size_t)r*DD + c;
  Qo[o] = q*cs + rq*sn;
  Ko[o] = k*cs + rk*sn;
  Vo[o] = v;
}

// ---------------- flash attention ----------------
// Block: 64 queries x (head h, stream z). 256 threads.
// Thread: queries qp,qp+1 (qp=(t>>3)*2), key/dim slice j=t&7.
// Online softmax across key tiles of 64.
__global__ __launch_bounds__(256) void fattn_kernel(
    const float* __restrict__ Qg, const float* __restrict__ Kg,
    const float* __restrict__ Vg, float* __restrict__ Out, float scale)
{
  __shared__ float Qs[64][68];
  __shared__ float Ks[64][68];
  __shared__ float Vs[64][64];
  __shared__ float Ss[64][76];
  int t = threadIdx.x;
  int h = blockIdx.y, z = blockIdx.z;
  int q0 = blockIdx.x * 64;
  size_t base = (size_t)z*KM*DD + (size_t)h*HD;
#pragma unroll
  for (int p = 0; p < 4; ++p) {
    int idx = p*256 + t;
    int row = idx >> 4, f4 = (idx & 15)*4;
    *(float4*)&Qs[row][f4] = *(const float4*)&Qg[base + (size_t)(q0+row)*DD + f4];
  }
  int j = t & 7;
  int qp = (t >> 3) * 2;
  float m0 = -1e30f, m1 = -1e30f, l0 = 0.f, l1 = 0.f;
  float o0[8] = {}, o1[8] = {};
  for (int kt = 0; kt < KM; kt += 64) {
    __syncthreads();
#pragma unroll
    for (int p = 0; p < 4; ++p) {
      int idx = p*256 + t;
      int row = idx >> 4, f4 = (idx & 15)*4;
      float4 kv = *(const float4*)&Kg[base + (size_t)(kt+row)*DD + f4];
      float4 vv = *(const float4*)&Vg[base + (size_t)(kt+row)*DD + f4];
      *(float4*)&Ks[row][f4] = kv;
      *(float4*)&Vs[row][f4] = vv;
    }
    __syncthreads();
    float s0[8] = {}, s1[8] = {};
#pragma unroll 4
    for (int dc = 0; dc < 64; dc += 4) {
      float4 qa = *(float4*)&Qs[qp][dc];
      float4 qb = *(float4*)&Qs[qp+1][dc];
#pragma unroll
      for (int kk = 0; kk < 8; ++kk) {
        float4 kv = *(float4*)&Ks[kk*8+j][dc];
        s0[kk] += qa.x*kv.x + qa.y*kv.y + qa.z*kv.z + qa.w*kv.w;
        s1[kk] += qb.x*kv.x + qb.y*kv.y + qb.z*kv.z + qb.w*kv.w;
      }
    }
    float ml0 = -1e30f, ml1 = -1e30f;
#pragma unroll
    for (int kk = 0; kk < 8; ++kk) {
      s0[kk] *= scale; s1[kk] *= scale;
      ml0 = fmaxf(ml0, s0[kk]); ml1 = fmaxf(ml1, s1[kk]);
    }
#pragma unroll
    for (int mk = 1; mk < 8; mk <<= 1) {
      ml0 = fmaxf(ml0, __shfl_xor(ml0, mk));
      ml1 = fmaxf(ml1, __shfl_xor(ml1, mk));
    }
    float mn0 = fmaxf(m0, ml0), mn1 = fmaxf(m1, ml1);
    float al0 = __expf(m0 - mn0), al1 = __expf(m1 - mn1);
    m0 = mn0; m1 = mn1;
    float ps0 = 0.f, ps1 = 0.f;
#pragma unroll
    for (int kk = 0; kk < 8; ++kk) {
      float p0 = __expf(s0[kk] - mn0), p1 = __expf(s1[kk] - mn1);
      Ss[qp][kk*8+j] = p0; Ss[qp+1][kk*8+j] = p1;
      ps0 += p0; ps1 += p1;
    }
#pragma unroll
    for (int mk = 1; mk < 8; mk <<= 1) {
      ps0 += __shfl_xor(ps0, mk);
      ps1 += __shfl_xor(ps1, mk);
    }
    l0 = l0*al0 + ps0; l1 = l1*al1 + ps1;
#pragma unroll
    for (int u = 0; u < 8; ++u) { o0[u] *= al0; o1[u] *= al1; }
    __syncthreads();
    int dbase = j*8;
#pragma unroll 4
    for (int k = 0; k < 64; ++k) {
      float p0 = Ss[qp][k], p1 = Ss[qp+1][k];
      float4 va = *(float4*)&Vs[k][dbase];
      float4 vb = *(float4*)&Vs[k][dbase+4];
      o0[0] += p0*va.x; o0[1] += p0*va.y; o0[2] += p0*va.z; o0[3] += p0*va.w;
      o0[4] += p0*vb.x; o0[5] += p0*vb.y; o0[6] += p0*vb.z; o0[7] += p0*vb.w;
      o1[0] += p1*va.x; o1[1] += p1*va.y; o1[2] += p1*va.z; o1[3] += p1*va.w;
      o1[4] += p1*vb.x; o1[5] += p1*vb.y; o1[6] += p1*vb.z; o1[7] += p1*vb.w;
    }
  }
  float r0 = 1.f/l0, r1 = 1.f/l1;
  size_t ob0 = base + (size_t)(q0+qp)*DD + j*8;
  size_t ob1 = ob0 + DD;
  float4 w0 = { o0[0]*r0, o0[1]*r0, o0[2]*r0, o0[3]*r0 };
  float4 w1 = { o0[4]*r0, o0[5]*r0, o0[6]*r0, o0[7]*r0 };
  float4 w2 = { o1[0]*r1, o1[1]*r1, o1[2]*r1, o1[3]*r1 };
  float4 w3 = { o1[4]*r1, o1[5]*r1, o1[6]*r1, o1[7]*r1 };
  *(float4*)&Out[ob0]     = w0;
  *(float4*)&Out[ob0 + 4] = w1;
  *(float4*)&Out[ob1]     = w2;
  *(float4*)&Out[ob1 + 4] = w3;
}

// ---------------- in-place LayerNorm + exact GELU over width 512 ----------------
__global__ __launch_bounds__(256) void ln_gelu_kernel(
    float* __restrict__ Hb, const float* __restrict__ g,
    const float* __restrict__ be)
{
  __shared__ float red[256];
  int r = blockIdx.x, t = threadIdx.x;
  float x0 = Hb[(size_t)r*512 + t];
  float x1 = Hb[(size_t)r*512 + 256 + t];
  red[t] = x0 + x1; __syncthreads();
  for (int s2 = 128; s2 > 0; s2 >>= 1) { if (t < s2) red[t] += red[t+s2]; __syncthreads(); }
  float mu = red[0] * (1.f/512.f); __syncthreads();
  float d0 = x0 - mu, d1 = x1 - mu;
  red[t] = d0*d0 + d1*d1; __syncthreads();
  for (int s2 = 128; s2 > 0; s2 >>= 1) { if (t < s2) red[t] += red[t+s2]; __syncthreads(); }
  float rstd = rsqrtf(red[0]*(1.f/512.f) + 1e-5f);
  float h0 = d0*rstd*g[t] + be[t];
  float h1 = d1*rstd*g[256+t] + be[256+t];
  h0 = 0.5f*h0*(1.f + erff(h0*0.70710678118f));
  h1 = 0.5f*h1*(1.f + erff(h1*0.70710678118f));
  Hb[(size_t)r*512 + t] = h0;
  Hb[(size_t)r*512 + 256 + t] = h1;
}

// ---------------- final head 2 ----------------
__global__ __launch_bounds__(256) void head2_kernel(
    const float* __restrict__ Hb, const float* __restrict__ w,
    const float* __restrict__ b, float* __restrict__ out)
{
  int r = blockIdx.x*256 + threadIdx.x;   // 8192 rows
  float acc = b[0];
#pragma unroll
  for (int k = 0; k < 64; ++k) acc += Hb[(size_t)r*64 + k]*w[k];
  out[r] = 1.f/(1.f + expf(-acc));
}

// ---------------- host ----------------
static void launch_gemm(const float* A, const float* A2, int K1, int K,
                        const float* W, const float* bias, float* C, int O,
                        int Nrows, const float* resid, float scale, int epi,
                        hipStream_t stream)
{
  dim3 grid(Nrows/64, O/64);
  gemm_w_kernel<<<grid, 256, 0, stream>>>(A, A2, K1, K, W, bias, C, O, resid, scale, epi);
}

extern "C" void kernel_launch(void* const* d_in, const int* in_sizes, int n_in,
                              void* d_out, int out_size, void* d_ws, size_t ws_size,
                              hipStream_t stream)
{
  (void)in_sizes; (void)n_in; (void)out_size; (void)ws_size;
  const float* fa      = (const float*)d_in[0];
  const float* fb      = (const float*)d_in[1];
  const int*   matches = (const int*)d_in[2];
  const float* ka      = (const float*)d_in[3];
  const float* kb      = (const float*)d_in[4];
  const float* lam     = (const float*)d_in[5];
  const float* beta    = (const float*)d_in[6];
  const float* Wr      = (const float*)d_in[7];
  const float* pW1     = (const float*)d_in[8];
  const float* pb1     = (const float*)d_in[9];
  const float* pW2     = (const float*)d_in[10];
  const float* pb2     = (const float*)d_in[11];
  const float* sWqkv   = (const float*)d_in[12];
  const float* sbqkv   = (const float*)d_in[13];
  const float* sWo     = (const float*)d_in[14];
  const float* sbo     = (const float*)d_in[15];
  const float* sW1     = (const float*)d_in[16];
  const float* sb1     = (const float*)d_in[17];
  const float* sg      = (const float*)d_in[18];
  const float* sbe     = (const float*)d_in[19];
  const float* sW2     = (const float*)d_in[20];
  const float* sb2     = (const float*)d_in[21];
  const float* cWqk    = (const float*)d_in[22];
  const float* cbqk    = (const float*)d_in[23];
  const float* cWv     = (const float*)d_in[24];
  const float* cbv     = (const float*)d_in[25];
  const float* cWo     = (const float*)d_in[26];
  const float* cbo     = (const float*)d_in[27];
  const float* cW1     = (const float*)d_in[28];
  const float* cb1     = (const float*)d_in[29];
  const float* cgw     = (const float*)d_in[30];
  const float* cbe     = (const float*)d_in[31];
  const float* cW2     = (const float*)d_in[32];
  const float* cb2     = (const float*)d_in[33];

  float* ws = (float*)d_ws;
  float* DCAT  = ws;                       // 4,194,304
  float* ENC0  = ws + 4194304;             // 1,048,576
  float* ENC1  = ws + 5242880;             // 1,048,576
  float* XY0   = ws + 6291456;             // 16,384
  float* XY1   = ws + 6307840;             // 16,384
  float* ROWS  = ws + 6324224;             // 8,192
  float* RRA   = ws + 6332416;             // 2,048
  float* RRB   = ws + 6334464;             // 2,048
  float* PAP   = ws + 6336512;             // 2,048
  float* POOL  = ws + 6338560;             // 25,165,824

  // CG-phase aliases
  float* KMAT = POOL;                  // 8,388,608
  float* FBUF = POOL + 8388608;        // 2,097,152
  float* XB   = POOL + 10485760;
  float* RB   = POOL + 12582912;
  float* PB   = POOL + 14680064;
  float* APB  = POOL + 16777216;
  // transformer-phase aliases
  float* QKV  = POOL;                  // 16384x768
  float* QR   = POOL + 12582912;
  float* KR   = POOL + 16777216;
  float* VB   = POOL + 20971520;
  float* ATTO = POOL;
  float* MSG  = POOL + 4194304;
  float* H1   = POOL + 8388608;        // 16384x512
  // cross-phase aliases
  float* QKB   = POOL;
  float* VB2   = POOL + 4194304;
  float* ATTO2 = POOL + 8388608;
  float* MSG2  = POOL + 12582912;
  float* H1C   = POOL + 16777216;
  float* HBUF  = POOL;                 // 8192x64

  const float sc = 0.35355339059327373f;   // 64^-0.25

  // ---- gather / posenc / Kmat ----
  gather_kernel<<<BN, 256, 0, stream>>>(fa, fb, matches, ka, kb, FBUF, XY0, XY1);
  posenc_kernel<<<BN, 64, 0, stream>>>(XY0, Wr, ENC0);
  posenc_kernel<<<BN, 64, 0, stream>>>(XY1, Wr, ENC1);
  kmat_kernel<<<BN, 256, 0, stream>>>(XY0, beta, KMAT, ROWS);

  // ---- CG solve (Kmat + lam I) X = F ----
  cg_init_kernel<<<BN, 256, 0, stream>>>(FBUF, XB, RB, PB);
  zero_kernel<<<8, 256, 0, stream>>>(RRA, BB*DD);
  cg_dot_kernel<<<BB*256, 256, 0, stream>>>(RB, RB, RRA);
  for (int it = 0; it < CG_ITERS; ++it) {
    gemm_bat_kernel<<<dim3(16,4,BB), 256, 0, stream>>>(KMAT, PB, APB, lam, nullptr);
    zero_kernel<<<8, 256, 0, stream>>>(PAP, BB*DD);
    cg_dot_kernel<<<BB*256, 256, 0, stream>>>(PB, APB, PAP);
    cg_update_xr_kernel<<<BN, 256, 0, stream>>>(XB, RB, PB, APB, RRA, PAP);
    zero_kernel<<<8, 256, 0, stream>>>(RRB, BB*DD);
    cg_dot_kernel<<<BB*256, 256, 0, stream>>>(RB, RB, RRB);
    cg_update_p_kernel<<<BN, 256, 0, stream>>>(PB, RB, RRA, RRB);
    copy_kernel<<<8, 256, 0, stream>>>(RRA, RRB, BB*DD);
  }

  // ---- d0 = f_i ; d1 = rownorm(Kmat) @ C ----
  copy_kernel<<<BN, 256, 0, stream>>>(DCAT, FBUF, BN*DD);
  gemm_bat_kernel<<<dim3(16,4,BB), 256, 0, stream>>>(KMAT, XB, DCAT + (size_t)BN*DD, nullptr, ROWS);

  // ---- transformer layers ----
  for (int l = 0; l < NLAYER; ++l) {
    launch_gemm(DCAT, nullptr, DD, DD, sWqkv + (size_t)l*768*DD, sbqkv + l*768,
                QKV, 768, N2, nullptr, 1.f, 0, stream);
    rope_split_kernel<<<N2, 256, 0, stream>>>(QKV, ENC0, ENC1, QR, KR, VB);
    fattn_kernel<<<dim3(16, HH, 16), 256, 0, stream>>>(QR, KR, VB, ATTO, 0.125f);
    launch_gemm(ATTO, nullptr, DD, DD, sWo + (size_t)l*DD*DD, sbo + l*DD,
                MSG, DD, N2, nullptr, 1.f, 0, stream);
    launch_gemm(DCAT, MSG, DD, 512, sW1 + (size_t)l*512*512, sb1 + l*512,
                H1, 512, N2, nullptr, 1.f, 0, stream);
    ln_gelu_kernel<<<N2, 256, 0, stream>>>(H1, sg + l*512, sbe + l*512);
    launch_gemm(H1, nullptr, 512, 512, sW2 + (size_t)l*DD*512, sb2 + l*DD,
                DCAT, DD, N2, DCAT, 1.f, 0, stream);
    // cross block
    launch_gemm(DCAT, nullptr, DD, DD, cWqk + (size_t)l*DD*DD, cbqk + l*DD,
                QKB, DD, N2, nullptr, sc, 1, stream);
    launch_gemm(DCAT, nullptr, DD, DD, cWv + (size_t)l*DD*DD, cbv + l*DD,
                VB2, DD, N2, nullptr, 1.f, 0, stream);
    fattn_kernel<<<dim3(16, HH, BB), 256, 0, stream>>>(QKB, QKB + (size_t)BN*DD,
                VB2 + (size_t)BN*DD, ATTO2, 1.f);
    fattn_kernel<<<dim3(16, HH, BB), 256, 0, stream>>>(QKB + (size_t)BN*DD, QKB,
                VB2, ATTO2 + (size_t)BN*DD, 1.f);
    launch_gemm(ATTO2, nullptr, DD, DD, cWo + (size_t)l*DD*DD, cbo + l*DD,
                MSG2, DD, N2, nullptr, 1.f, 0, stream);
    launch_gemm(DCAT, MSG2, DD, 512, cW1 + (size_t)l*512*512, cb1 + l*512,
                H1C, 512, N2, nullptr, 1.f, 0, stream);
    ln_gelu_kernel<<<N2, 256, 0, stream>>>(H1C, cgw + l*512, cbe + l*512);
    launch_gemm(H1C, nullptr, 512, 512, cW2 + (size_t)l*DD*512, cb2 + l*DD,
                DCAT, DD, N2, DCAT, 1.f, 0, stream);
  }

  // ---- head ----
  launch_gemm(DCAT, nullptr, DD, DD, pW1, pb1, HBUF, 64, BN, nullptr, 1.f, 2, stream);
  head2_kernel<<<BN/256, 256, 0, stream>>>(HBUF, pW2, pb2, (float*)d_out);
}

// Round 3
// 1936.311 us; speedup vs baseline: 11.0161x; 2.7356x over previous
//
#include <hip/hip_runtime.h>
#include <math.h>

// Problem constants
#define BB 8
#define MM 2048
#define KM 1024
#define DD 256
#define HH 4
#define HD 64
#define NLAYER 2
#define BN (BB*KM)        // 8192 rows per "decoder half"
#define N2 (2*BN)         // 16384 rows d0||d1
#define CG_ITERS 12

typedef __bf16 bf16;
typedef __bf16 bf16x8 __attribute__((ext_vector_type(8)));
typedef float  floatx4 __attribute__((ext_vector_type(4)));
#define MFMA16(a,b,c) __builtin_amdgcn_mfma_f32_16x16x32_bf16(a,b,c,0,0,0)

__device__ __forceinline__ float softplusf(float x) {
  return fmaxf(x, 0.f) + log1pf(expf(-fabsf(x)));
}

// stage 8 elements (convert to bf16 if needed), 16B LDS store
__device__ __forceinline__ void stage8(bf16* dst, const float* src) {
  float4 a = *(const float4*)src;
  float4 b = *(const float4*)(src + 4);
  bf16x8 v = { (bf16)a.x,(bf16)a.y,(bf16)a.z,(bf16)a.w,
               (bf16)b.x,(bf16)b.y,(bf16)b.z,(bf16)b.w };
  *(bf16x8*)dst = v;
}
__device__ __forceinline__ void stage8(bf16* dst, const bf16* src) {
  *(uint4*)dst = *(const uint4*)src;
}

// ---------------- gather: f_i, xy0, xy1 ----------------
__global__ __launch_bounds__(256) void gather_kernel(
    const float* __restrict__ fa, const float* __restrict__ fb,
    const int* __restrict__ matches, const float* __restrict__ ka,
    const float* __restrict__ kb, float* __restrict__ F,
    float* __restrict__ xy0, float* __restrict__ xy1)
{
  int si = blockIdx.x;             // s*1024 + i
  int s  = si >> 10;
  int t  = threadIdx.x;
  int ia = matches[(size_t)si*2+0];
  int ib = matches[(size_t)si*2+1];
  F[(size_t)si*DD + t] = fb[((size_t)s*MM + ib)*DD + t]
                       - fa[((size_t)s*MM + ia)*DD + t];
  if (t == 0) {
    xy0[(size_t)si*2+0] = ka[((size_t)s*MM + ia)*2+0];
    xy0[(size_t)si*2+1] = ka[((size_t)s*MM + ia)*2+1];
    xy1[(size_t)si*2+0] = kb[((size_t)s*MM + ib)*2+0];
    xy1[(size_t)si*2+1] = kb[((size_t)s*MM + ib)*2+1];
  }
}

// ---------------- positional encoding ----------------
__global__ __launch_bounds__(64) void posenc_kernel(
    const float* __restrict__ xy, const float* __restrict__ Wr,
    float* __restrict__ enc)
{
  int si = blockIdx.x; int s = si >> 10, i = si & 1023;
  int d = threadIdx.x; int p = d >> 1;
  float x = xy[(size_t)si*2], y = xy[(size_t)si*2+1];
  float pr = Wr[p*2]*x + Wr[p*2+1]*y;
  enc[(((size_t)s*2+0)*KM + i)*HD + d] = cosf(pr);
  enc[(((size_t)s*2+1)*KM + i)*HD + d] = sinf(pr);
}

// ---------------- Kmat (bf16) + rowsum (fp32) ----------------
__global__ __launch_bounds__(256) void kmat_kernel(
    const float* __restrict__ xy0, const float* __restrict__ beta_ptr,
    bf16* __restrict__ Km, float* __restrict__ rowsum)
{
  __shared__ float red[256];
  int si = blockIdx.x; int s = si >> 10;
  int t = threadIdx.x;
  float beta_r = softplusf(beta_ptr[0]);
  float xi = xy0[(size_t)si*2], yi = xy0[(size_t)si*2+1];
  const float* xys = xy0 + (size_t)s*KM*2;
  float sum = 0.f;
  for (int jj = 0; jj < 4; ++jj) {
    int j = jj*256 + t;
    float dx = xi - xys[j*2], dy = yi - xys[j*2+1];
    float v = expf(-beta_r*(dx*dx + dy*dy));
    bf16 vb = (bf16)v;
    Km[(size_t)si*KM + j] = vb;
    sum += (float)vb;
  }
  red[t] = sum; __syncthreads();
  for (int s2 = 128; s2 > 0; s2 >>= 1) { if (t < s2) red[t] += red[t+s2]; __syncthreads(); }
  if (t == 0) rowsum[si] = red[0] + 1e-6f;
}

// ---------------- MFMA GEMM: C = [A1|A2] @ W.T (+bias)(*scale)(/rowdiv)(+resid) ----
// 128x128 tile, 4 waves, BK=32. resid_mode: 0 none, 1 +resid, 2 +softplus(lam)*resid
// dotout: if nonnull, atomicAdd per output row of sum(resid*out) (CG pap).
template<typename TA, typename TW, typename TO>
__global__ __launch_bounds__(256) void mm_kernel(
    const TA* __restrict__ A1, const TA* __restrict__ A2, int K1, int K,
    const TW* __restrict__ W, const float* __restrict__ bias,
    TO* __restrict__ C, int O, float scale,
    const float* __restrict__ resid, int resid_mode, const float* __restrict__ lam_ptr,
    const float* __restrict__ rowdiv, float* __restrict__ dotout,
    long zsA1, long zsW, long zsC, long zsR)
{
  __shared__ __align__(16) bf16 Al[128*40];
  __shared__ __align__(16) bf16 Wl[128*40];
  int tid = threadIdx.x;
  int z = blockIdx.z;
  const TA* A1z = A1 + (size_t)z*zsA1;
  const TW* Wz  = W  + (size_t)z*zsW;
  TO* Cz = C + (size_t)z*zsC;
  const float* Rz = resid ? (resid + (size_t)z*zsR) : (const float*)0;
  int row0 = blockIdx.x*128, col0 = blockIdx.y*128;
  int lane = tid & 63, w = tid >> 6;
  int wr = (w>>1)*64, wc = (w&1)*64;
  int lm = lane & 15, lq = lane >> 4;
  floatx4 acc[4][4];
#pragma unroll
  for (int mb = 0; mb < 4; ++mb)
#pragma unroll
    for (int nb = 0; nb < 4; ++nb) acc[mb][nb] = (floatx4){0.f,0.f,0.f,0.f};
  for (int k0 = 0; k0 < K; k0 += 32) {
    const TA* Asrc; int astr, kb;
    if (k0 < K1) { Asrc = A1z; astr = K1; kb = k0; }
    else         { Asrc = A2;  astr = K - K1; kb = k0 - K1; }
#pragma unroll
    for (int p = 0; p < 2; ++p) {
      int idx = p*256 + tid;
      int row = idx >> 2, c8 = (idx & 3)*8;
      stage8(&Al[row*40 + c8], &Asrc[(size_t)(row0+row)*astr + kb + c8]);
      stage8(&Wl[row*40 + c8], &Wz[(size_t)(col0+row)*K + k0 + c8]);
    }
    __syncthreads();
    bf16x8 af[4], bf_[4];
#pragma unroll
    for (int mb = 0; mb < 4; ++mb)
      af[mb] = *(bf16x8*)&Al[(wr + mb*16 + lm)*40 + lq*8];
#pragma unroll
    for (int nb = 0; nb < 4; ++nb)
      bf_[nb] = *(bf16x8*)&Wl[(wc + nb*16 + lm)*40 + lq*8];
#pragma unroll
    for (int mb = 0; mb < 4; ++mb)
#pragma unroll
      for (int nb = 0; nb < 4; ++nb)
        acc[mb][nb] = MFMA16(af[mb], bf_[nb], acc[mb][nb]);
    __syncthreads();
  }
  float lamv = 1.f;
  if (resid_mode == 2) lamv = softplusf(lam_ptr[0]) + 1e-6f;
#pragma unroll
  for (int mb = 0; mb < 4; ++mb) {
    float dsum[4] = {0.f,0.f,0.f,0.f};
#pragma unroll
    for (int nb = 0; nb < 4; ++nb) {
#pragma unroll
      for (int r = 0; r < 4; ++r) {
        int grow = row0 + wr + mb*16 + lq*4 + r;
        int gcol = col0 + wc + nb*16 + lm;
        float v = acc[mb][nb][r];
        if (bias) v += bias[gcol];
        v *= scale;
        if (rowdiv) v /= rowdiv[(size_t)z*KM + grow];
        if (Rz) {
          float rv = Rz[(size_t)grow*O + gcol];
          v += lamv * rv;
          dsum[r] += rv * v;
        }
        Cz[(size_t)grow*O + gcol] = (TO)v;
      }
    }
    if (dotout) {
#pragma unroll
      for (int r = 0; r < 4; ++r) {
        float s = dsum[r];
        s += __shfl_xor(s,1); s += __shfl_xor(s,2);
        s += __shfl_xor(s,4); s += __shfl_xor(s,8);
        if (lm == 0)
          atomicAdd(&dotout[(size_t)z*DD + row0 + wr + mb*16 + lq*4 + r], s);
      }
    }
  }
}

// ---------------- fp32 tile GEMM (head only, O=64) ----------------
__global__ __launch_bounds__(256) void gemm_f32_kernel(
    const float* __restrict__ A, const float* __restrict__ A2, int K1, int K,
    const float* __restrict__ W, const float* __restrict__ bias,
    float* __restrict__ C, int O,
    const float* __restrict__ resid, float scale, int epi)
{
  __shared__ float As[32][68];
  __shared__ float Ws[32][68];
  int t = threadIdx.x;
  int row0 = blockIdx.x * 64;
  int col0 = blockIdx.y * 64;
  int ti = t & 15, tj = t >> 4;
  float acc[4][4] = {};
  int K2 = K - K1;
  for (int k0 = 0; k0 < K; k0 += 32) {
    const float* src; int stride; int kb;
    if (k0 < K1) { src = A;  stride = K1; kb = k0; }
    else         { src = A2; stride = K2; kb = k0 - K1; }
#pragma unroll
    for (int p = 0; p < 2; ++p) {
      int idx = p*256 + t;
      int ar = idx >> 3, af = (idx & 7)*4;
      float4 av = *(const float4*)&src[(size_t)(row0+ar)*stride + kb + af];
      As[af+0][ar] = av.x; As[af+1][ar] = av.y;
      As[af+2][ar] = av.z; As[af+3][ar] = av.w;
      float4 wv = *(const float4*)&W[(size_t)(col0+ar)*K + k0 + af];
      Ws[af+0][ar] = wv.x; Ws[af+1][ar] = wv.y;
      Ws[af+2][ar] = wv.z; Ws[af+3][ar] = wv.w;
    }
    __syncthreads();
#pragma unroll
    for (int kk = 0; kk < 32; ++kk) {
      float4 a4 = *(float4*)&As[kk][ti*4];
      float4 b4 = *(float4*)&Ws[kk][tj*4];
      float a[4] = {a4.x, a4.y, a4.z, a4.w};
      float b[4] = {b4.x, b4.y, b4.z, b4.w};
#pragma unroll
      for (int x = 0; x < 4; ++x)
#pragma unroll
        for (int y = 0; y < 4; ++y) acc[x][y] += a[x]*b[y];
    }
    __syncthreads();
  }
#pragma unroll
  for (int x = 0; x < 4; ++x) {
    int r = row0 + ti*4 + x;
#pragma unroll
    for (int y = 0; y < 4; ++y) {
      int c = col0 + tj*4 + y;
      float v = acc[x][y] + bias[c];
      if (epi == 1) v *= scale;
      else if (epi == 2) v = fmaxf(v, 0.f);
      if (resid) v += resid[(size_t)r*O + c];
      C[(size_t)r*O + c] = v;
    }
  }
}

// ---------------- transpose-init: PT=RT=F^T, XT=0, RRA=rowdot ----------------
__global__ __launch_bounds__(256) void tinit_kernel(
    const float* __restrict__ F, float* __restrict__ PT, float* __restrict__ RT,
    float* __restrict__ XT, float* __restrict__ RRA)
{
  __shared__ float Ls[64][68];
  int t = threadIdx.x;
  int k0 = blockIdx.x*64, n0 = blockIdx.y*64, z = blockIdx.z;
#pragma unroll
  for (int p = 0; p < 4; ++p) {
    int idx = p*256 + t;
    int kr = idx >> 4, c4 = (idx & 15)*4;
    *(float4*)&Ls[kr][c4] = *(const float4*)&F[((size_t)z*KM + k0+kr)*DD + n0 + c4];
  }
  __syncthreads();
#pragma unroll
  for (int p = 0; p < 4; ++p) {
    int idx = p*256 + t;
    int nl = idx >> 4, k4 = (idx & 15)*4;
    float4 v = { Ls[k4+0][nl], Ls[k4+1][nl], Ls[k4+2][nl], Ls[k4+3][nl] };
    size_t o = ((size_t)z*DD + n0+nl)*KM + k0 + k4;
    *(float4*)&PT[o] = v;
    *(float4*)&RT[o] = v;
    float4 zr = {0.f,0.f,0.f,0.f};
    *(float4*)&XT[o] = zr;
    float s = v.x*v.x + v.y*v.y + v.z*v.z + v.w*v.w;
    s += __shfl_xor(s,1); s += __shfl_xor(s,2);
    s += __shfl_xor(s,4); s += __shfl_xor(s,8);
    if ((t & 15) == 0) atomicAdd(&RRA[z*DD + n0 + nl], s);
  }
}

// ---------------- CG updates (one block per (z,n) row of 1024) ----------------
__global__ __launch_bounds__(256) void cg_xr_kernel(
    float* __restrict__ XT, float* __restrict__ RT,
    const float* __restrict__ PT, const float* __restrict__ APT,
    const float* __restrict__ RRA, const float* __restrict__ PAP,
    float* __restrict__ RRB)
{
  __shared__ float red[256];
  int row = blockIdx.x;
  int t = threadIdx.x;
  float den = PAP[row], num = RRA[row];
  float alpha = (den > 1e-30f) ? num/den : 0.f;
  size_t base = (size_t)row*KM;
  float s = 0.f;
#pragma unroll
  for (int u = 0; u < 4; ++u) {
    size_t i = base + u*256 + t;
    float r = RT[i] - alpha*APT[i];
    XT[i] += alpha*PT[i];
    RT[i] = r;
    s += r*r;
  }
  red[t] = s; __syncthreads();
  for (int s2 = 128; s2 > 0; s2 >>= 1) { if (t < s2) red[t] += red[t+s2]; __syncthreads(); }
  if (t == 0) RRB[row] = red[0];
}

__global__ __launch_bounds__(256) void cg_p_kernel(
    float* __restrict__ PT, const float* __restrict__ RT,
    float* __restrict__ RRA, const float* __restrict__ RRB,
    float* __restrict__ PAP)
{
  int row = blockIdx.x;
  int t = threadIdx.x;
  float o = RRA[row], nn = RRB[row];
  float beta = (o > 1e-30f) ? nn/o : 0.f;
  size_t base = (size_t)row*KM;
#pragma unroll
  for (int u = 0; u < 4; ++u) {
    size_t i = base + u*256 + t;
    PT[i] = RT[i] + beta*PT[i];
  }
  __syncthreads();
  if (t == 0) { RRA[row] = nn; PAP[row] = 0.f; }
}

// ---------------- misc ----------------
__global__ __launch_bounds__(256) void zero_kernel(float* __restrict__ p, int n) {
  int idx = blockIdx.x*256 + threadIdx.x;
  if (idx < n) p[idx] = 0.f;
}
__global__ __launch_bounds__(256) void copy_kernel(
    float* __restrict__ dst, const float* __restrict__ src, int n)
{
  size_t idx = (size_t)blockIdx.x*256 + threadIdx.x;
  if (idx < (size_t)n) dst[idx] = src[idx];
}

// ---------------- RoPE + qkv split (bf16 in/out) ----------------
__global__ __launch_bounds__(256) void rope_split_kernel(
    const bf16* __restrict__ qkv, const float* __restrict__ enc0,
    const float* __restrict__ enc1, bf16* __restrict__ Qo,
    bf16* __restrict__ Ko, bf16* __restrict__ Vo)
{
  int r = blockIdx.x;            // stream*KM + i ; stream in [0,16)
  int c = threadIdx.x;           // h*64+d
  int ts = r >> 10, i = r & 1023;
  int h = c >> 6, d = c & 63;
  const float* enc = (ts < BB) ? enc0 : enc1;
  int s = (ts < BB) ? ts : ts - BB;
  float cs = enc[(((size_t)s*2+0)*KM + i)*HD + d];
  float sn = enc[(((size_t)s*2+1)*KM + i)*HD + d];
  size_t bse = (size_t)r*768 + (size_t)h*192;
  float q = (float)qkv[bse + d*3 + 0];
  float k = (float)qkv[bse + d*3 + 1];
  float v = (float)qkv[bse + d*3 + 2];
  int dp = d ^ 1;
  float qp = (float)qkv[bse + dp*3 + 0];
  float kp = (float)qkv[bse + dp*3 + 1];
  float rq = (d & 1) ? qp : -qp;
  float rk = (d & 1) ? kp : -kp;
  size_t o = (size_t)r*DD + c;
  Qo[o] = (bf16)(q*cs + rq*sn);
  Ko[o] = (bf16)(k*cs + rk*sn);
  Vo[o] = (bf16)v;
}

// ---------------- MFMA flash attention ----------------
// Block: 64 queries x (head, stream). 4 waves; wave w owns query rows 16w..16w+15.
__global__ __launch_bounds__(256) void mha_kernel(
    const bf16* __restrict__ Qg, const bf16* __restrict__ Kg,
    const bf16* __restrict__ Vg, bf16* __restrict__ Og, float scale)
{
  __shared__ __align__(16) bf16 Qs[64*72];   // Q staging; reused as P
  __shared__ __align__(16) bf16 Ks[64*72];
  __shared__ __align__(16) bf16 Vt[64*80];   // V^T with XOR-swizzled key blocks
  int tid = threadIdx.x;
  int lane = tid & 63, w = tid >> 6;
  int lm = lane & 15, lq = lane >> 4;
  int h = blockIdx.y, z = blockIdx.z;
  int q0 = blockIdx.x * 64;
  size_t base = ((size_t)z*KM)*DD + (size_t)h*HD;
#pragma unroll
  for (int p = 0; p < 2; ++p) {
    int idx = p*256 + tid;
    int row = idx >> 3, c8 = (idx & 7)*8;
    *(uint4*)&Qs[row*72 + c8] = *(const uint4*)&Qg[base + (size_t)(q0+row)*DD + c8];
  }
  __syncthreads();
  bf16x8 qa0 = *(bf16x8*)&Qs[(w*16 + lm)*72 + lq*8];
  bf16x8 qa1 = *(bf16x8*)&Qs[(w*16 + lm)*72 + 32 + lq*8];
  float m_[4], l_[4];
  floatx4 oacc[4];
#pragma unroll
  for (int r = 0; r < 4; ++r) { m_[r] = -1e30f; l_[r] = 0.f; }
#pragma unroll
  for (int db = 0; db < 4; ++db) oacc[db] = (floatx4){0.f,0.f,0.f,0.f};
  for (int kt = 0; kt < KM; kt += 64) {
    __syncthreads();
#pragma unroll
    for (int p = 0; p < 2; ++p) {
      int idx = p*256 + tid;
      int row = idx >> 3, c8 = (idx & 7)*8;
      *(uint4*)&Ks[row*72 + c8] = *(const uint4*)&Kg[base + (size_t)(kt+row)*DD + c8];
      uint4 vv = *(const uint4*)&Vg[base + (size_t)(kt+row)*DD + c8];
      bf16 vtmp[8] __attribute__((aligned(16)));
      *(uint4*)vtmp = vv;
      int kb = row >> 3, klo = row & 7;
#pragma unroll
      for (int jj = 0; jj < 8; ++jj) {
        int d = c8 + jj;
        Vt[d*80 + (((kb ^ (d>>3)) & 7)*8) + klo] = vtmp[jj];
      }
    }
    __syncthreads();
    floatx4 s[4];
#pragma unroll
    for (int nb = 0; nb < 4; ++nb) {
      s[nb] = (floatx4){0.f,0.f,0.f,0.f};
      bf16x8 b0 = *(bf16x8*)&Ks[(nb*16 + lm)*72 + lq*8];
      bf16x8 b1 = *(bf16x8*)&Ks[(nb*16 + lm)*72 + 32 + lq*8];
      s[nb] = MFMA16(qa0, b0, s[nb]);
      s[nb] = MFMA16(qa1, b1, s[nb]);
    }
    float al[4], ps[4];
#pragma unroll
    for (int r = 0; r < 4; ++r) {
      float a0 = s[0][r]*scale, a1 = s[1][r]*scale;
      float a2 = s[2][r]*scale, a3 = s[3][r]*scale;
      s[0][r]=a0; s[1][r]=a1; s[2][r]=a2; s[3][r]=a3;
      float v = fmaxf(fmaxf(a0,a1), fmaxf(a2,a3));
      v = fmaxf(v, __shfl_xor(v,1));
      v = fmaxf(v, __shfl_xor(v,2));
      v = fmaxf(v, __shfl_xor(v,4));
      v = fmaxf(v, __shfl_xor(v,8));
      float mn = fmaxf(m_[r], v);
      al[r] = __expf(m_[r] - mn);
      m_[r] = mn;
      ps[r] = 0.f;
    }
#pragma unroll
    for (int nb = 0; nb < 4; ++nb)
#pragma unroll
      for (int r = 0; r < 4; ++r) {
        float p = __expf(s[nb][r] - m_[r]);
        ps[r] += p;
        Qs[(w*16 + lq*4 + r)*72 + nb*16 + lm] = (bf16)p;
      }
#pragma unroll
    for (int r = 0; r < 4; ++r) {
      float v = ps[r];
      v += __shfl_xor(v,1); v += __shfl_xor(v,2);
      v += __shfl_xor(v,4); v += __shfl_xor(v,8);
      l_[r] = l_[r]*al[r] + v;
      oacc[0][r] *= al[r]; oacc[1][r] *= al[r];
      oacc[2][r] *= al[r]; oacc[3][r] *= al[r];
    }
    bf16x8 pa0 = *(bf16x8*)&Qs[(w*16 + lm)*72 + lq*8];
    bf16x8 pa1 = *(bf16x8*)&Qs[(w*16 + lm)*72 + 32 + lq*8];
#pragma unroll
    for (int db = 0; db < 4; ++db) {
      int dd = db*16 + lm;
      bf16x8 v0 = *(bf16x8*)&Vt[dd*80 + (((lq  ) ^ (dd>>3)) & 7)*8];
      bf16x8 v1 = *(bf16x8*)&Vt[dd*80 + (((lq+4) ^ (dd>>3)) & 7)*8];
      oacc[db] = MFMA16(pa0, v0, oacc[db]);
      oacc[db] = MFMA16(pa1, v1, oacc[db]);
    }
  }
#pragma unroll
  for (int db = 0; db < 4; ++db)
#pragma unroll
    for (int r = 0; r < 4; ++r) {
      int grow = q0 + w*16 + lq*4 + r;
      float v = oacc[db][r] / l_[r];
      Og[base + (size_t)grow*DD + db*16 + lm] = (bf16)v;
    }
}

// ---------------- in-place LayerNorm + exact GELU over width 512 ----------------
__global__ __launch_bounds__(256) void ln_gelu_kernel(
    float* __restrict__ Hb, const float* __restrict__ g,
    const float* __restrict__ be)
{
  __shared__ float red[256];
  int r = blockIdx.x, t = threadIdx.x;
  float x0 = Hb[(size_t)r*512 + t];
  float x1 = Hb[(size_t)r*512 + 256 + t];
  red[t] = x0 + x1; __syncthreads();
  for (int s2 = 128; s2 > 0; s2 >>= 1) { if (t < s2) red[t] += red[t+s2]; __syncthreads(); }
  float mu = red[0] * (1.f/512.f); __syncthreads();
  float d0 = x0 - mu, d1 = x1 - mu;
  red[t] = d0*d0 + d1*d1; __syncthreads();
  for (int s2 = 128; s2 > 0; s2 >>= 1) { if (t < s2) red[t] += red[t+s2]; __syncthreads(); }
  float rstd = rsqrtf(red[0]*(1.f/512.f) + 1e-5f);
  float h0 = d0*rstd*g[t] + be[t];
  float h1 = d1*rstd*g[256+t] + be[256+t];
  h0 = 0.5f*h0*(1.f + erff(h0*0.70710678118f));
  h1 = 0.5f*h1*(1.f + erff(h1*0.70710678118f));
  Hb[(size_t)r*512 + t] = h0;
  Hb[(size_t)r*512 + 256 + t] = h1;
}

// ---------------- final head 2 ----------------
__global__ __launch_bounds__(256) void head2_kernel(
    const float* __restrict__ Hb, const float* __restrict__ w,
    const float* __restrict__ b, float* __restrict__ out)
{
  int r = blockIdx.x*256 + threadIdx.x;   // 8192 rows
  float acc = b[0];
#pragma unroll
  for (int k = 0; k < 64; ++k) acc += Hb[(size_t)r*64 + k]*w[k];
  out[r] = 1.f/(1.f + expf(-acc));
}

extern "C" void kernel_launch(void* const* d_in, const int* in_sizes, int n_in,
                              void* d_out, int out_size, void* d_ws, size_t ws_size,
                              hipStream_t stream)
{
  (void)in_sizes; (void)n_in; (void)out_size; (void)ws_size;
  const float* fa      = (const float*)d_in[0];
  const float* fb      = (const float*)d_in[1];
  const int*   matches = (const int*)d_in[2];
  const float* ka      = (const float*)d_in[3];
  const float* kb      = (const float*)d_in[4];
  const float* lam     = (const float*)d_in[5];
  const float* beta    = (const float*)d_in[6];
  const float* Wr      = (const float*)d_in[7];
  const float* pW1     = (const float*)d_in[8];
  const float* pb1     = (const float*)d_in[9];
  const float* pW2     = (const float*)d_in[10];
  const float* pb2     = (const float*)d_in[11];
  const float* sWqkv   = (const float*)d_in[12];
  const float* sbqkv   = (const float*)d_in[13];
  const float* sWo     = (const float*)d_in[14];
  const float* sbo     = (const float*)d_in[15];
  const float* sW1     = (const float*)d_in[16];
  const float* sb1     = (const float*)d_in[17];
  const float* sg      = (const float*)d_in[18];
  const float* sbe     = (const float*)d_in[19];
  const float* sW2     = (const float*)d_in[20];
  const float* sb2     = (const float*)d_in[21];
  const float* cWqk    = (const float*)d_in[22];
  const float* cbqk    = (const float*)d_in[23];
  const float* cWv     = (const float*)d_in[24];
  const float* cbv     = (const float*)d_in[25];
  const float* cWo     = (const float*)d_in[26];
  const float* cbo     = (const float*)d_in[27];
  const float* cW1     = (const float*)d_in[28];
  const float* cb1     = (const float*)d_in[29];
  const float* cgw     = (const float*)d_in[30];
  const float* cbe     = (const float*)d_in[31];
  const float* cW2     = (const float*)d_in[32];
  const float* cb2     = (const float*)d_in[33];

  char* wsb = (char*)d_ws;
  float* DCAT = (float*)wsb;                      // 16,777,216 B (16384x256 f32)
  float* ENC0 = (float*)(wsb + 16777216);
  float* ENC1 = (float*)(wsb + 20971520);
  float* XY0  = (float*)(wsb + 25165824);
  float* XY1  = (float*)(wsb + 25231360);
  float* ROWS = (float*)(wsb + 25296896);
  float* RRA  = (float*)(wsb + 25329664);
  float* RRB  = (float*)(wsb + 25337856);
  float* PAP  = (float*)(wsb + 25346048);
  char*  POOL = wsb + 25354240;
  const size_t SLOT = 8388608;
  // CG phase
  bf16*  KMATH = (bf16*)POOL;                    // slots 0-1
  float* FBUF  = (float*)(POOL + 2*SLOT);
  float* PT    = (float*)(POOL + 3*SLOT);
  float* RT    = (float*)(POOL + 4*SLOT);
  float* XT    = (float*)(POOL + 5*SLOT);
  float* APT   = (float*)(POOL + 6*SLOT);
  // transformer phase
  bf16*  QKV   = (bf16*)POOL;                    // slots 0-2
  bf16*  QR    = (bf16*)(POOL + 3*SLOT);
  bf16*  KR    = (bf16*)(POOL + 4*SLOT);
  bf16*  VB    = (bf16*)(POOL + 5*SLOT);
  bf16*  ATTO  = (bf16*)POOL;                    // slot 0 (QKV dead)
  float* MSG   = (float*)(POOL + 1*SLOT);        // slots 1-2
  float* H1    = (float*)(POOL + 6*SLOT);        // slots 6-9
  bf16*  QKB   = (bf16*)POOL;
  bf16*  VB2   = (bf16*)(POOL + 1*SLOT);
  bf16*  ATTO2 = (bf16*)(POOL + 2*SLOT);
  float* MSG2  = (float*)(POOL + 3*SLOT);        // slots 3-4
  float* H1C   = H1;
  float* HBUF  = (float*)POOL;

  const float sc = 0.35355339059327373f;         // 64^-0.25

  // ---- gather / posenc / Kmat ----
  gather_kernel<<<BN, 256, 0, stream>>>(fa, fb, matches, ka, kb, FBUF, XY0, XY1);
  posenc_kernel<<<BN, 64, 0, stream>>>(XY0, Wr, ENC0);
  posenc_kernel<<<BN, 64, 0, stream>>>(XY1, Wr, ENC1);
  kmat_kernel<<<BN, 256, 0, stream>>>(XY0, beta, KMATH, ROWS);

  // ---- CG (transposed state) ----
  zero_kernel<<<24, 256, 0, stream>>>(RRA, 6144);       // RRA,RRB,PAP contiguous
  tinit_kernel<<<dim3(16,4,BB), 256, 0, stream>>>(FBUF, PT, RT, XT, RRA);
  for (int it = 0; it < CG_ITERS; ++it) {
    mm_kernel<float,bf16,float><<<dim3(2,8,BB), 256, 0, stream>>>(
        PT, (const float*)0, 1024, 1024, KMATH, (const float*)0, APT, 1024, 1.f,
        PT, 2, lam, (const float*)0, PAP, 262144, 1048576, 262144, 262144);
    cg_xr_kernel<<<2048, 256, 0, stream>>>(XT, RT, PT, APT, RRA, PAP, RRB);
    cg_p_kernel<<<2048, 256, 0, stream>>>(PT, RT, RRA, RRB, PAP);
  }

  // ---- d0 = f_i ; d1 = rownorm(Kmat) @ C ----
  copy_kernel<<<8192, 256, 0, stream>>>(DCAT, FBUF, BN*DD);
  mm_kernel<bf16,float,float><<<dim3(8,2,BB), 256, 0, stream>>>(
      KMATH, (const bf16*)0, 1024, 1024, XT, (const float*)0,
      DCAT + (size_t)BN*DD, 256, 1.f,
      (const float*)0, 0, (const float*)0, ROWS, (float*)0,
      1048576, 262144, 262144, 0);

  // ---- transformer layers ----
  for (int l = 0; l < NLAYER; ++l) {
    mm_kernel<float,float,bf16><<<dim3(128,6,1), 256, 0, stream>>>(
        DCAT, (const float*)0, 256, 256, sWqkv + (size_t)l*768*256, sbqkv + l*768,
        QKV, 768, 1.f, (const float*)0, 0, (const float*)0, (const float*)0, (float*)0, 0,0,0,0);
    rope_split_kernel<<<N2, 256, 0, stream>>>(QKV, ENC0, ENC1, QR, KR, VB);
    mha_kernel<<<dim3(16,HH,16), 256, 0, stream>>>(QR, KR, VB, ATTO, 0.125f);
    mm_kernel<bf16,float,float><<<dim3(128,2,1), 256, 0, stream>>>(
        ATTO, (const bf16*)0, 256, 256, sWo + (size_t)l*256*256, sbo + l*256,
        MSG, 256, 1.f, (const float*)0, 0, (const float*)0, (const float*)0, (float*)0, 0,0,0,0);
    mm_kernel<float,float,float><<<dim3(128,4,1), 256, 0, stream>>>(
        DCAT, MSG, 256, 512, sW1 + (size_t)l*512*512, sb1 + l*512,
        H1, 512, 1.f, (const float*)0, 0, (const float*)0, (const float*)0, (float*)0, 0,0,0,0);
    ln_gelu_kernel<<<N2, 256, 0, stream>>>(H1, sg + l*512, sbe + l*512);
    mm_kernel<float,float,float><<<dim3(128,2,1), 256, 0, stream>>>(
        H1, (const float*)0, 512, 512, sW2 + (size_t)l*256*512, sb2 + l*256,
        DCAT, 256, 1.f, DCAT, 1, (const float*)0, (const float*)0, (float*)0, 0,0,0,0);
    // cross block
    mm_kernel<float,float,bf16><<<dim3(128,2,1), 256, 0, stream>>>(
        DCAT, (const float*)0, 256, 256, cWqk + (size_t)l*256*256, cbqk + l*256,
        QKB, 256, sc, (const float*)0, 0, (const float*)0, (const float*)0, (float*)0, 0,0,0,0);
    mm_kernel<float,float,bf16><<<dim3(128,2,1), 256, 0, stream>>>(
        DCAT, (const float*)0, 256, 256, cWv + (size_t)l*256*256, cbv + l*256,
        VB2, 256, 1.f, (const float*)0, 0, (const float*)0, (const float*)0, (float*)0, 0,0,0,0);
    mha_kernel<<<dim3(16,HH,BB), 256, 0, stream>>>(
        QKB, QKB + (size_t)BN*DD, VB2 + (size_t)BN*DD, ATTO2, 1.f);
    mha_kernel<<<dim3(16,HH,BB), 256, 0, stream>>>(
        QKB + (size_t)BN*DD, QKB, VB2, ATTO2 + (size_t)BN*DD, 1.f);
    mm_kernel<bf16,float,float><<<dim3(128,2,1), 256, 0, stream>>>(
        ATTO2, (const bf16*)0, 256, 256, cWo + (size_t)l*256*256, cbo + l*256,
        MSG2, 256, 1.f, (const float*)0, 0, (const float*)0, (const float*)0, (float*)0, 0,0,0,0);
    mm_kernel<float,float,float><<<dim3(128,4,1), 256, 0, stream>>>(
        DCAT, MSG2, 256, 512, cW1 + (size_t)l*512*512, cb1 + l*512,
        H1C, 512, 1.f, (const float*)0, 0, (const float*)0, (const float*)0, (float*)0, 0,0,0,0);
    ln_gelu_kernel<<<N2, 256, 0, stream>>>(H1C, cgw + l*512, cbe + l*512);
    mm_kernel<float,float,float><<<dim3(128,2,1), 256, 0, stream>>>(
        H1C, (const float*)0, 512, 512, cW2 + (size_t)l*256*512, cb2 + l*256,
        DCAT, 256, 1.f, DCAT, 1, (const float*)0, (const float*)0, (float*)0, 0,0,0,0);
  }

  // ---- head ----
  gemm_f32_kernel<<<dim3(128,1), 256, 0, stream>>>(
      DCAT, (const float*)0, 256, 256, pW1, pb1, HBUF, 64, (const float*)0, 1.f, 2);
  head2_kernel<<<32, 256, 0, stream>>>(HBUF, pW2, pb2, (float*)d_out);
}